// Round 11
// baseline (1451.078 us; speedup 1.0000x reference)
//
#include <hip/hip_runtime.h>

typedef unsigned short u16;
typedef __attribute__((ext_vector_type(4))) float floatx4;
typedef __attribute__((ext_vector_type(8))) short shortx8;
typedef __attribute__((ext_vector_type(4))) short shortx4;

#define NOPS 8192
#define NMS  512
#define CQ   2560   // op qkv cols: q | k0 | v0 | k2 | v2
#define CM   1536   // machine qkv cols: q | k1 | v1
#define NE2  65536
#define TOPC (NOPS*512)
#define TMC  (NMS*512)

__device__ __forceinline__ float bf2f(u16 u){ return __uint_as_float(((unsigned)u)<<16); }
__device__ __forceinline__ u16 f2bf(float f){
  unsigned u = __float_as_uint(f);
  u += 0x7FFFu + ((u>>16)&1u);
  return (u16)(u>>16);
}
__device__ __forceinline__ float wred(float v){
  #pragma unroll
  for (int o=32;o;o>>=1) v += __shfl_xor(v,o,64);
  return v;
}
__device__ __forceinline__ float geluf(float x){
  return 0.5f*x*(1.f+erff(x*0.70710678118654752f));
}
// block (s,s2) reduction -> one pair at pstat[slot]
__device__ __forceinline__ void block_stat_out2(float s, float s2, float* pstat, int slot){
  __shared__ float sb[8];
  s = wred(s); s2 = wred(s2);
  int wv = threadIdx.x >> 6;
  if ((threadIdx.x & 63) == 0){ sb[wv*2] = s; sb[wv*2+1] = s2; }
  __syncthreads();
  if (threadIdx.x == 0){
    float a = 0.f, b = 0.f;
    int nw = blockDim.x >> 6;
    for (int i=0;i<nw;++i){ a += sb[i*2]; b += sb[i*2+1]; }
    pstat[slot*2]   = a;
    pstat[slot*2+1] = b;
  }
}

// ---------------- edge multiplicity, no atomics / no pre-zero ----------------
// Cn[n][ml] = #edges (n, machine ml of its graph); Ct[m][nl] = transpose view.
__global__ __launch_bounds__(256) void cnt2_k(const int* __restrict__ s1, float* __restrict__ Ct,
                                              float* __restrict__ Cn){
  int idx = blockIdx.x*256 + threadIdx.x;      // 524288
  int n = idx >> 6, l = idx & 63;
  const int* row = s1 + n*8;
  int cnt = 0;
  #pragma unroll
  for (int j=0;j<8;++j) cnt += ((row[j] & 63) == l);
  float f = (float)cnt;
  Cn[(size_t)n*64 + l] = f;
  int b = n >> 10, nl = n & 1023;
  Ct[(size_t)((b<<6) + l)*1024 + nl] = f;
}

// ---------------- W_out: f32 [6][K][N] -> bf16 transposed [6][N][K] ----------------
__global__ __launch_bounds__(256) void twout_k(const float* __restrict__ src, u16* __restrict__ dst){
  __shared__ u16 t[64][65];
  int l = blockIdx.x, kb = blockIdx.y*64, nb = blockIdx.z*64;
  const float* s = src + (size_t)l*262144;
  u16* d = dst + (size_t)l*262144;
  int tx = threadIdx.x & 63, ty4 = threadIdx.x >> 6;
  #pragma unroll 4
  for (int p=0;p<16;++p){
    int k = ty4 + p*4;
    t[k][tx] = f2bf(s[(size_t)(kb+k)*512 + nb + tx]);
  }
  __syncthreads();
  #pragma unroll 4
  for (int p=0;p<16;++p){
    int n = ty4 + p*4;
    d[(size_t)(nb+n)*512 + kb + tx] = t[tx][n];
  }
}

// ---------------- Wq transpose into Wc rows 0..511 ----------------
__global__ __launch_bounds__(256) void tq_k(const float* __restrict__ Wq,
                                            u16* __restrict__ Wc_op_t, u16* __restrict__ Wc_m_t){
  __shared__ u16 tl[64][65];
  int blk = blockIdx.x;
  int l = blk >> 1, side = blk & 1;
  const float* s = Wq + (size_t)blk*262144;
  u16* d = side ? (Wc_m_t + (size_t)l*CM*512) : (Wc_op_t + (size_t)l*CQ*512);
  int kb = blockIdx.y*64, nb = blockIdx.z*64;
  int tx = threadIdx.x & 63, ty4 = threadIdx.x >> 6;
  #pragma unroll 4
  for (int p=0;p<16;++p){
    int k = ty4 + p*4;
    tl[k][tx] = f2bf(s[(size_t)(kb+k)*512 + nb + tx]);
  }
  __syncthreads();
  #pragma unroll 4
  for (int p=0;p<16;++p){
    int n = ty4 + p*4;
    d[(size_t)(nb+n)*512 + kb + tx] = tl[tx][n];
  }
}

// ---------------- q biases ----------------
__global__ void qb_k(const float* __restrict__ bq, float* bias_op, float* bias_m){
  int i = blockIdx.x*blockDim.x + threadIdx.x;
  if (i >= 3072) return;
  int l = i >> 10, side = (i >> 9) & 1, f = i & 511;
  float v = bq[(l*2+side)*512 + f];
  if (side==0) bias_op[l*CQ + f] = v; else bias_m[l*CM + f] = v;
}

// ---------------- relation combine via MFMA: out[e][cc] = Rel^T x W^T, grid (144,4) ----------------
__global__ __launch_bounds__(256) void combine3_k(const float* __restrict__ Wk, const float* __restrict__ Wv,
                                                  const float* __restrict__ Ar, const float* __restrict__ Mr,
                                                  u16* __restrict__ Wc_op_t, u16* __restrict__ Wc_m_t){
  __shared__ u16 As[64*72];
  __shared__ u16 Bs[128*72];
  int gx = blockIdx.x;
  int l = gx/48; int rem = gx - l*48; int s = rem >> 3; int h = rem & 7;
  int side = (s < 4) ? 0 : 1;
  int r = (s < 4) ? (s+1) : (s-3);
  int useK = side==0 ? (s==0 || s==2) : (s==4);
  int rel  = side==0 ? ((s<2)?0:2) : 1;
  const float* W   = (useK ? Wk : Wv) + (size_t)(l*2+side)*262144;
  const float* Rel = (useK ? Ar : Mr) + ((size_t)(l*3+rel)*8 + h)*4096;
  int h64 = h*64;
  u16* Wt = side ? (Wc_m_t + (size_t)l*CM*512) : (Wc_op_t + (size_t)l*CQ*512);
  int rbase = r*512 + h64;
  int cc0 = blockIdx.y * 128;
  int tid = threadIdx.x, lane = tid & 63, wave = tid >> 6;
  {
    int d = tid >> 2, e0 = (tid & 3) * 16;
    #pragma unroll
    for (int j=0;j<16;++j) As[(e0+j)*72 + d] = f2bf(Rel[d*64 + e0 + j]);
  }
  {
    int ccl = tid >> 1, d0 = (tid & 1) * 32;
    const float* src = W + (size_t)(cc0+ccl)*512 + h64 + d0;
    #pragma unroll
    for (int j=0;j<32;j+=4){
      floatx4 v = *(const floatx4*)(src + j);
      shortx4 sv;
      #pragma unroll
      for (int e=0;e<4;++e) sv[e] = (short)f2bf(v[e]);
      *(shortx4*)(Bs + ccl*72 + d0 + j) = sv;
    }
  }
  __syncthreads();
  int wm = wave & 1, wn = wave >> 1;
  int mrow = lane & 15, quad = lane >> 4;
  floatx4 acc[2][4];
  #pragma unroll
  for (int a=0;a<2;++a)
    #pragma unroll
    for (int b=0;b<4;++b) acc[a][b] = (floatx4){0.f,0.f,0.f,0.f};
  #pragma unroll
  for (int ks=0; ks<2; ++ks){
    shortx8 af[2], bf[4];
    #pragma unroll
    for (int mt=0;mt<2;++mt) af[mt] = *(const shortx8*)(As + (wm*32 + mt*16 + mrow)*72 + ks*32 + quad*8);
    #pragma unroll
    for (int nt=0;nt<4;++nt) bf[nt] = *(const shortx8*)(Bs + (wn*64 + nt*16 + mrow)*72 + ks*32 + quad*8);
    #pragma unroll
    for (int mt=0;mt<2;++mt)
      #pragma unroll
      for (int nt=0;nt<4;++nt)
        acc[mt][nt] = __builtin_amdgcn_mfma_f32_16x16x32_bf16(af[mt], bf[nt], acc[mt][nt], 0, 0, 0);
  }
  #pragma unroll
  for (int mt=0;mt<2;++mt){
    #pragma unroll
    for (int nt=0;nt<4;++nt){
      int ccl = wn*64 + nt*16 + mrow;
      #pragma unroll
      for (int r2=0;r2<4;++r2){
        int e = wm*32 + mt*16 + quad*4 + r2;
        Wt[(size_t)(rbase + e)*512 + cc0 + ccl] = f2bf(acc[mt][nt][r2]);
      }
    }
  }
}
// bias row of the combine (cc==512)
__global__ void cbias_k(const float* __restrict__ bk, const float* __restrict__ bv,
                        const float* __restrict__ Ar, const float* __restrict__ Mr,
                        float* bias_op, float* bias_m){
  int gx = blockIdx.x; int e = threadIdx.x;
  int l = gx/48; int rem = gx - l*48; int s = rem >> 3; int h = rem & 7;
  int side = (s < 4) ? 0 : 1;
  int r = (s < 4) ? (s+1) : (s-3);
  int useK = side==0 ? (s==0 || s==2) : (s==4);
  int rel  = side==0 ? ((s<2)?0:2) : 1;
  const float* bb  = (useK ? bk : bv) + (size_t)(l*2+side)*512 + h*64;
  const float* Rel = (useK ? Ar : Mr) + ((size_t)(l*3+rel)*8 + h)*4096;
  float acc = 0.f;
  for (int d=0; d<64; ++d) acc += bb[d]*Rel[d*64 + e];
  float* bias = side ? (bias_m + l*CM) : (bias_op + l*CQ);
  bias[r*512 + h*64 + e] = acc;
}

// ---------------- merged embedding (op+m) + per-block LN partials ----------------
__global__ __launch_bounds__(256) void embed2_k(const float* __restrict__ Xop, const float* __restrict__ Wop,
                                                const float* __restrict__ bop, float* __restrict__ Yop,
                                                const float* __restrict__ Xm, const float* __restrict__ Wm,
                                                const float* __restrict__ bm_, float* __restrict__ Ym,
                                                float* pstat, float* pstat_m){
  int bid = blockIdx.x;
  const float *X, *W, *bias; float *Y, *ps; int K, total, nb, lb;
  if (bid < 1024){ X=Xop; W=Wop; bias=bop; Y=Yop; ps=pstat;   K=16; total=TOPC; nb=1024; lb=bid; }
  else           { X=Xm;  W=Wm;  bias=bm_; Y=Ym;  ps=pstat_m; K=8;  total=TMC;  nb=128;  lb=bid-1024; }
  float s = 0.f, s2 = 0.f;
  for (int idx = lb*256 + threadIdx.x; idx < total; idx += nb*256){
    int n = idx >> 9, f = idx & 511;
    float v = bias[f];
    for (int c=0;c<K;++c) v += X[n*K+c] * W[c*512+f];
    Y[idx] = v;
    s += v; s2 += v*v;
  }
  block_stat_out2(s, s2, ps, lb);
}

// ---------------- merged graph-LN apply (op+m), with in-block pstat reduction ----------------
__global__ __launch_bounds__(256) void ln2_k(const float* __restrict__ src_op, float* __restrict__ dst_op,
                                             u16* __restrict__ dbf_op, const float* __restrict__ w_op,
                                             const float* __restrict__ b_op,
                                             const float* __restrict__ src_m, float* __restrict__ dst_m,
                                             u16* __restrict__ dbf_m, const float* __restrict__ w_m,
                                             const float* __restrict__ b_m,
                                             const float* __restrict__ pstat, const float* __restrict__ pstat_m){
  int bid = blockIdx.x;
  const float *src, *w, *b, *ps; float* dst; u16* dbf; int total4, nb, lb, nblk; float inv_n;
  if (bid < 1024){ src=src_op; dst=dst_op; dbf=dbf_op; w=w_op; b=b_op; ps=pstat;
                   total4=TOPC/4; nb=1024; lb=bid; nblk=1024; inv_n=1.f/TOPC; }
  else           { src=src_m;  dst=dst_m;  dbf=dbf_m;  w=w_m;  b=b_m;  ps=pstat_m;
                   total4=TMC/4;  nb=128;  lb=bid-1024; nblk=128; inv_n=1.f/TMC; }
  // in-block redundant stats reduction
  __shared__ float sb[8];
  __shared__ float mr[2];
  float s = 0.f, s2 = 0.f;
  for (int i = threadIdx.x; i < nblk; i += 256){ s += ps[2*i]; s2 += ps[2*i+1]; }
  s = wred(s); s2 = wred(s2);
  int wv = threadIdx.x >> 6;
  if ((threadIdx.x & 63) == 0){ sb[wv*2] = s; sb[wv*2+1] = s2; }
  __syncthreads();
  if (threadIdx.x == 0){
    float a = 0.f, bsum = 0.f;
    for (int i=0;i<4;++i){ a += sb[i*2]; bsum += sb[i*2+1]; }
    float mean = a * inv_n;
    float var  = fmaxf(bsum * inv_n - mean*mean, 0.f);
    mr[0] = mean;
    mr[1] = 1.f/(sqrtf(var) + 1e-5f);
  }
  __syncthreads();
  float mean = mr[0], rinv = mr[1];
  const floatx4* s4 = (const floatx4*)src;
  floatx4* d4 = (floatx4*)dst;
  shortx4* db4 = (shortx4*)dbf;
  const floatx4* w4 = (const floatx4*)w;
  const floatx4* b4 = (const floatx4*)b;
  for (int i = lb*256 + threadIdx.x; i < total4; i += nb*256){
    int f = i & 127;
    floatx4 v = s4[i], wv2 = w4[f], bv = b4[f];
    shortx4 sv;
    #pragma unroll
    for (int e=0;e<4;++e){ v[e] = (v[e]-mean)*rinv*wv2[e] + bv[e]; sv[e] = (short)f2bf(v[e]); }
    d4[i] = v;
    db4[i] = sv;
  }
}

// ---------------- merged gated residual (op+m) + per-block LN partials ----------------
__global__ __launch_bounds__(256) void gate2_k(float* __restrict__ y_op, const float* __restrict__ x_op,
                                               const float* __restrict__ bo_op, const float* __restrict__ sk_op,
                                               float* __restrict__ y_m, const float* __restrict__ x_m,
                                               const float* __restrict__ bo_m, const float* __restrict__ sk_m,
                                               float* pstat, float* pstat_m){
  int bid = blockIdx.x;
  float *y, *ps; const float *x, *bo, *sk; int total4, nb, lb;
  if (bid < 1024){ y=y_op; x=x_op; bo=bo_op; sk=sk_op; ps=pstat;   total4=TOPC/4; nb=1024; lb=bid; }
  else           { y=y_m;  x=x_m;  bo=bo_m;  sk=sk_m;  ps=pstat_m; total4=TMC/4;  nb=128;  lb=bid-1024; }
  float g = 1.f/(1.f+expf(-(*sk)));
  floatx4* y4 = (floatx4*)y;
  const floatx4* x4 = (const floatx4*)x;
  const floatx4* b4 = (const floatx4*)bo;
  float s = 0.f, s2 = 0.f;
  for (int i = lb*256 + threadIdx.x; i < total4; i += nb*256){
    floatx4 yv = y4[i], xv = x4[i], bv = b4[i & 127];
    #pragma unroll
    for (int e=0;e<4;++e){
      float o = g*(yv[e]+bv[e]) + (2.f-g)*xv[e];
      yv[e] = o;
      s += o; s2 += o*o;
    }
    y4[i] = yv;
  }
  block_stat_out2(s, s2, ps, lb);
}

// ---------------- m97-style GEMM core + merged dual-GEMM kernel ----------------
__device__ __forceinline__ void gemm_core(u16* As, u16* Bs, const u16* __restrict__ A,
                                          const u16* __restrict__ Bt, const float* __restrict__ bias,
                                          void* __restrict__ Cp, int N, int K, int out_bf16,
                                          int bx, int by){
  const int tid = threadIdx.x;
  const int lane = tid & 63, wave = tid >> 6;
  const int bm = by * 128, bn = bx * 128;
  const int wm = wave & 1, wn = wave >> 1;
  const int mrow = lane & 15, quad = lane >> 4;
  const u16* Ab = A + (size_t)bm*K;
  const u16* Bb = Bt + (size_t)bn*K;
  floatx4 acc[4][4];
  #pragma unroll
  for (int a=0;a<4;++a)
    #pragma unroll
    for (int b=0;b<4;++b) acc[a][b] = (floatx4){0.f,0.f,0.f,0.f};
  const int r0 = tid >> 2, c0 = (tid & 3) * 8;
  const int r1 = (tid+256) >> 2, c1 = ((tid+256) & 3) * 8;
  const int lds0 = wave*512;
  const int lds1 = wave*512 + 2048;
  for (int k0 = 0; k0 < K; k0 += 32){
    __builtin_amdgcn_global_load_lds((const __attribute__((address_space(1))) void*)(Ab + (size_t)r0*K + k0 + c0),
                                     (__attribute__((address_space(3))) void*)(As + lds0), 16, 0, 0);
    __builtin_amdgcn_global_load_lds((const __attribute__((address_space(1))) void*)(Ab + (size_t)r1*K + k0 + c1),
                                     (__attribute__((address_space(3))) void*)(As + lds1), 16, 0, 0);
    __builtin_amdgcn_global_load_lds((const __attribute__((address_space(1))) void*)(Bb + (size_t)r0*K + k0 + c0),
                                     (__attribute__((address_space(3))) void*)(Bs + lds0), 16, 0, 0);
    __builtin_amdgcn_global_load_lds((const __attribute__((address_space(1))) void*)(Bb + (size_t)r1*K + k0 + c1),
                                     (__attribute__((address_space(3))) void*)(Bs + lds1), 16, 0, 0);
    __syncthreads();
    shortx8 af[4], bf[4];
    #pragma unroll
    for (int mt=0;mt<4;++mt) af[mt] = *(const shortx8*)(As + (wm*64 + mt*16 + mrow)*32 + quad*8);
    #pragma unroll
    for (int nt=0;nt<4;++nt) bf[nt] = *(const shortx8*)(Bs + (wn*64 + nt*16 + mrow)*32 + quad*8);
    #pragma unroll
    for (int mt=0;mt<4;++mt)
      #pragma unroll
      for (int nt=0;nt<4;++nt)
        acc[mt][nt] = __builtin_amdgcn_mfma_f32_16x16x32_bf16(af[mt], bf[nt], acc[mt][nt], 0, 0, 0);
    __syncthreads();
  }
  #pragma unroll
  for (int mt=0;mt<4;++mt){
    #pragma unroll
    for (int nt=0;nt<4;++nt){
      int col = bn + wn*64 + nt*16 + mrow;
      float bval = bias ? bias[col] : 0.f;
      #pragma unroll
      for (int r2=0;r2<4;++r2){
        int row = bm + wm*64 + mt*16 + quad*4 + r2;
        float v = acc[mt][nt][r2] + bval;
        if (out_bf16) ((u16*)Cp)[(size_t)row*N + col] = f2bf(v);
        else          ((float*)Cp)[(size_t)row*N + col] = v;
      }
    }
  }
}
__global__ __launch_bounds__(256) void gemm2_k(const u16* A1, const u16* B1, const float* bias1, void* C1,
                                               int N1, int ob1, int ntx1, int nblk1,
                                               const u16* A2, const u16* B2, const float* bias2, void* C2,
                                               int N2, int ob2, int ntx2, int K){
  __shared__ u16 As[128*32];
  __shared__ u16 Bs[128*32];
  int id = blockIdx.x;
  if (id < nblk1) gemm_core(As, Bs, A1, B1, bias1, C1, N1, K, ob1, id % ntx1, id / ntx1);
  else { int j = id - nblk1; gemm_core(As, Bs, A2, B2, bias2, C2, N2, K, ob2, j % ntx2, j / ntx2); }
}

// ---------------- merged score GEMMs + fused op-softmax ----------------
// z=0: S1 = q_op x k1^T -> in-block masked softmax (+precedes) -> W1, wpre, linv
// z=1: S2 = q_m x k2^T -> S2f (softmax deferred to agg12)
__global__ __launch_bounds__(256) void qk12_k(const u16* __restrict__ qkv_op, const u16* __restrict__ qkv_m,
                                              const float* __restrict__ prel, const float* __restrict__ Cn,
                                              u16* __restrict__ W1, float* __restrict__ wpre,
                                              float* __restrict__ linv, float* __restrict__ S2f){
  __shared__ __align__(16) char smem[36864];
  u16* As = (u16*)smem;             // 128*72
  u16* Bs = As + 128*72;            // 128*72
  float* Sbuf = (float*)smem;       // 128*65 floats, aliases staging after barrier
  int bh = blockIdx.y; int b = bh >> 3, h = bh & 7;
  int n0 = blockIdx.x * 128;
  int tid = threadIdx.x, lane = tid & 63, wave = tid >> 6;
  int mrow = lane & 15, quad = lane >> 4;
  if (blockIdx.z == 0){
    int wm = wave & 1, wn = wave >> 1;
    float p1 = prel[8 + h] * 0.125f;
    {
      int row = tid >> 1, col = (tid & 1) * 32;
      const u16* src = qkv_op + (size_t)(b*1024 + n0 + row)*CQ + h*64 + col;
      #pragma unroll
      for (int e=0;e<4;++e) *(shortx8*)(As + row*72 + col + e*8) = *(const shortx8*)(src + e*8);
    }
    {
      int row = tid >> 2, col = (tid & 3) * 16;
      const u16* src = qkv_m + (size_t)(b*64 + row)*CM + 512 + h*64 + col;
      *(shortx8*)(Bs + row*72 + col)     = *(const shortx8*)(src);
      *(shortx8*)(Bs + row*72 + col + 8) = *(const shortx8*)(src + 8);
    }
    __syncthreads();
    floatx4 acc[4][2];
    #pragma unroll
    for (int a=0;a<4;++a){ acc[a][0] = (floatx4){0,0,0,0}; acc[a][1] = (floatx4){0,0,0,0}; }
    #pragma unroll
    for (int ks=0; ks<2; ++ks){
      shortx8 af[4], bf[2];
      #pragma unroll
      for (int mt=0;mt<4;++mt) af[mt] = *(const shortx8*)(As + (wm*64 + mt*16 + mrow)*72 + ks*32 + quad*8);
      #pragma unroll
      for (int nt=0;nt<2;++nt) bf[nt] = *(const shortx8*)(Bs + (wn*32 + nt*16 + mrow)*72 + ks*32 + quad*8);
      #pragma unroll
      for (int mt=0;mt<4;++mt)
        #pragma unroll
        for (int nt=0;nt<2;++nt)
          acc[mt][nt] = __builtin_amdgcn_mfma_f32_16x16x32_bf16(af[mt], bf[nt], acc[mt][nt], 0, 0, 0);
    }
    __syncthreads();   // staging reads done; reuse smem for scores
    #pragma unroll
    for (int mt=0;mt<4;++mt){
      #pragma unroll
      for (int nt=0;nt<2;++nt){
        int m = wn*32 + nt*16 + mrow;
        #pragma unroll
        for (int r2=0;r2<4;++r2){
          int nl = wm*64 + mt*16 + quad*4 + r2;
          Sbuf[nl*65 + m] = acc[mt][nt][r2] * p1;
        }
      }
    }
    __syncthreads();
    if (tid < 128){
      int n_g = b*1024 + n0 + tid;
      int nl  = n0 + tid;             // local op index in graph
      float sp = -1e30f;
      if (nl > 0){
        float p0 = prel[h] * 0.125f;
        const u16* qp = qkv_op + (size_t)n_g*CQ + h*64;
        const u16* kp = qkv_op + (size_t)(n_g-1)*CQ + 512 + h*64;
        float d = 0.f;
        #pragma unroll
        for (int j=0;j<8;++j){
          shortx8 qa = *(const shortx8*)(qp + j*8);
          shortx8 ka = *(const shortx8*)(kp + j*8);
          #pragma unroll
          for (int e=0;e<8;++e) d += bf2f((u16)qa[e])*bf2f((u16)ka[e]);
        }
        sp = d * p0;
      }
      const float* crow = Cn + (size_t)n_g*64;
      float mx = sp;
      #pragma unroll
      for (int m=0;m<64;++m){
        if (crow[m] > 0.f) mx = fmaxf(mx, Sbuf[tid*65 + m]);
      }
      float L = 0.f;
      u16* wrow = W1 + ((size_t)n_g*8 + h)*64;
      #pragma unroll
      for (int m0=0;m0<64;m0+=4){
        shortx4 pv;
        #pragma unroll
        for (int e=0;e<4;++e){
          float c = crow[m0+e];
          float w = (c > 0.f) ? c*expf(Sbuf[tid*65 + m0+e]-mx) : 0.f;
          L += w;
          pv[e] = (short)f2bf(w);
        }
        *(shortx4*)(wrow + m0) = pv;
      }
      float ep = (nl > 0) ? expf(sp - mx) : 0.f;
      L += ep;
      wpre[(size_t)n_g*8 + h] = ep;
      linv[(size_t)n_g*8 + h] = 1.f/(L + 1e-16f);
    }
  } else {
    float p2 = prel[16 + h] * 0.125f;
    {
      int row = tid >> 2, col = (tid & 3) * 16;
      const u16* src = qkv_m + (size_t)(b*64+row)*CM + h*64 + col;
      *(shortx8*)(As + row*72 + col)     = *(const shortx8*)(src);
      *(shortx8*)(As + row*72 + col + 8) = *(const shortx8*)(src + 8);
    }
    {
      int row = tid >> 1, col = (tid & 1) * 32;
      const u16* src = qkv_op + (size_t)(b*1024 + n0 + row)*CQ + 1536 + h*64 + col;
      #pragma unroll
      for (int e=0;e<4;++e) *(shortx8*)(Bs + row*72 + col + e*8) = *(const shortx8*)(src + e*8);
    }
    __syncthreads();
    floatx4 acc[4][2];
    #pragma unroll
    for (int a=0;a<4;++a){ acc[a][0] = (floatx4){0,0,0,0}; acc[a][1] = (floatx4){0,0,0,0}; }
    #pragma unroll
    for (int ks=0; ks<2; ++ks){
      shortx8 af[4], bf[2];
      #pragma unroll
      for (int mt=0;mt<4;++mt) af[mt] = *(const shortx8*)(As + (mt*16 + mrow)*72 + ks*32 + quad*8);
      #pragma unroll
      for (int nt=0;nt<2;++nt) bf[nt] = *(const shortx8*)(Bs + (wave*32 + nt*16 + mrow)*72 + ks*32 + quad*8);
      #pragma unroll
      for (int mt=0;mt<4;++mt)
        #pragma unroll
        for (int nt=0;nt<2;++nt)
          acc[mt][nt] = __builtin_amdgcn_mfma_f32_16x16x32_bf16(af[mt], bf[nt], acc[mt][nt], 0, 0, 0);
    }
    #pragma unroll
    for (int mt=0;mt<4;++mt){
      #pragma unroll
      for (int nt=0;nt<2;++nt){
        int n = n0 + wave*32 + nt*16 + mrow;
        #pragma unroll
        for (int r2=0;r2<4;++r2){
          int m = mt*16 + quad*4 + r2;
          S2f[((size_t)(b*64 + m)*8 + h)*1024 + n] = acc[mt][nt][r2] * p2;
        }
      }
    }
  }
}

// ---------------- merged agg GEMMs: [0,512) op-side; [512,576) machine-side w/ fused softmax ----------------
__global__ __launch_bounds__(256) void agg12_k(const u16* __restrict__ W1, const u16* __restrict__ qkv_op,
                                               const u16* __restrict__ qkv_m, const float* __restrict__ wpre,
                                               const float* __restrict__ linv, u16* __restrict__ agg_op,
                                               const float* __restrict__ S2f, const float* __restrict__ Ct,
                                               u16* __restrict__ agg_m){
  __shared__ u16 As[128*72];
  __shared__ u16 Bs[64*72];
  __shared__ float mstat[128];
  int bid = blockIdx.x;
  int tid = threadIdx.x, lane = tid & 63, wave = tid >> 6;
  int wm = wave & 1, wn = wave >> 1;
  int mrow = lane & 15, quad = lane >> 4;
  if (bid < 512){
    int bh = bid >> 3; int b = bh >> 3, h = bh & 7;
    int n0 = (bid & 7) * 128;
    {
      int row = tid >> 1, col = (tid & 1) * 32;
      const u16* src = W1 + ((size_t)(b*1024 + n0 + row)*8 + h)*64 + col;
      #pragma unroll
      for (int e=0;e<4;++e) *(shortx8*)(As + row*72 + col + e*8) = *(const shortx8*)(src + e*8);
    }
    {
      int m = tid >> 2, dcol = (tid & 3) * 16;
      const u16* src = qkv_m + (size_t)(b*64 + m)*CM + 1024 + h*64 + dcol;
      shortx8 v0 = *(const shortx8*)(src);
      shortx8 v1 = *(const shortx8*)(src + 8);
      #pragma unroll
      for (int e=0;e<8;++e){ Bs[(dcol+e)*72 + m] = (u16)v0[e]; Bs[(dcol+8+e)*72 + m] = (u16)v1[e]; }
    }
    __syncthreads();
    floatx4 acc[4][2];
    #pragma unroll
    for (int a=0;a<4;++a){ acc[a][0] = (floatx4){0,0,0,0}; acc[a][1] = (floatx4){0,0,0,0}; }
    #pragma unroll
    for (int ks=0; ks<2; ++ks){
      shortx8 af[4], bf[2];
      #pragma unroll
      for (int mt=0;mt<4;++mt) af[mt] = *(const shortx8*)(As + (wm*64 + mt*16 + mrow)*72 + ks*32 + quad*8);
      #pragma unroll
      for (int nt=0;nt<2;++nt) bf[nt] = *(const shortx8*)(Bs + (wn*32 + nt*16 + mrow)*72 + ks*32 + quad*8);
      #pragma unroll
      for (int mt=0;mt<4;++mt)
        #pragma unroll
        for (int nt=0;nt<2;++nt)
          acc[mt][nt] = __builtin_amdgcn_mfma_f32_16x16x32_bf16(af[mt], bf[nt], acc[mt][nt], 0, 0, 0);
    }
    #pragma unroll
    for (int mt=0;mt<4;++mt){
      #pragma unroll
      for (int nt=0;nt<2;++nt){
        int d = wn*32 + nt*16 + mrow;
        #pragma unroll
        for (int r2=0;r2<4;++r2){
          int n = n0 + wm*64 + mt*16 + quad*4 + r2;
          size_t ng = (size_t)b*1024 + n;
          size_t ih = ng*8 + h;
          float v = acc[mt][nt][r2];
          if ((n & 1023) > 0) v += wpre[ih] * bf2f(qkv_op[(ng-1)*CQ + 1024 + h*64 + d]);
          v *= linv[ih];
          agg_op[ng*512 + h*64 + d] = f2bf(geluf(v));
        }
      }
    }
  } else {
    int bh = bid - 512; int b = bh >> 3, h = bh & 7;
    // fused machine softmax pass 1: per-m masked max + sum over 1024 n
    {
      int m = tid >> 2, q4 = tid & 3;
      const float* srow = S2f + ((size_t)(b*64+m)*8 + h)*1024;
      const float* crow = Ct + (size_t)(b*64+m)*1024;
      float mx = -1e30f;
      for (int n = q4*256; n < q4*256+256; ++n){
        if (crow[n] > 0.f) mx = fmaxf(mx, srow[n]);
      }
      mx = fmaxf(mx, __shfl_xor(mx,1,64));
      mx = fmaxf(mx, __shfl_xor(mx,2,64));
      float L = 0.f;
      for (int n = q4*256; n < q4*256+256; ++n){
        float c = crow[n];
        if (c > 0.f) L += c*expf(srow[n]-mx);
      }
      L += __shfl_xor(L,1,64);
      L += __shfl_xor(L,2,64);
      if (q4 == 0){ mstat[m*2] = mx; mstat[m*2+1] = 1.f/(L + 1e-16f); }
    }
    __syncthreads();
    floatx4 acc[2][2];
    acc[0][0]=(floatx4){0,0,0,0}; acc[0][1]=(floatx4){0,0,0,0};
    acc[1][0]=(floatx4){0,0,0,0}; acc[1][1]=(floatx4){0,0,0,0};
    const int arow = tid >> 2, acol = (tid & 3) * 8;
    const int nrow = tid >> 3, dcol = (tid & 7) * 8;
    const float* srow = S2f + ((size_t)(b*64+arow)*8 + h)*1024;
    const float* crow = Ct + (size_t)(b*64+arow)*1024;
    for (int ks = 0; ks < 32; ++ks){
      int nn0 = ks*32;
      {
        float mx = mstat[arow*2], inv = mstat[arow*2+1];
        shortx4 pv0, pv1;
        #pragma unroll
        for (int e=0;e<4;++e){
          float c0 = crow[nn0+acol+e],   s0v = srow[nn0+acol+e];
          float c1 = crow[nn0+acol+4+e], s1v = srow[nn0+acol+4+e];
          pv0[e] = (short)f2bf((c0 > 0.f) ? c0*expf(s0v-mx)*inv : 0.f);
          pv1[e] = (short)f2bf((c1 > 0.f) ? c1*expf(s1v-mx)*inv : 0.f);
        }
        *(shortx4*)(As + arow*40 + acol)     = pv0;
        *(shortx4*)(As + arow*40 + acol + 4) = pv1;
      }
      shortx8 vv = *(const shortx8*)(qkv_op + (size_t)(b*1024 + nn0 + nrow)*CQ + 2048 + h*64 + dcol);
      #pragma unroll
      for (int e=0;e<8;++e) Bs[(dcol+e)*40 + nrow] = (u16)vv[e];
      __syncthreads();
      shortx8 af[2], bf[2];
      #pragma unroll
      for (int mt=0;mt<2;++mt) af[mt] = *(const shortx8*)(As + (wm*32 + mt*16 + mrow)*40 + quad*8);
      #pragma unroll
      for (int nt=0;nt<2;++nt) bf[nt] = *(const shortx8*)(Bs + (wn*32 + nt*16 + mrow)*40 + quad*8);
      #pragma unroll
      for (int mt=0;mt<2;++mt)
        #pragma unroll
        for (int nt=0;nt<2;++nt)
          acc[mt][nt] = __builtin_amdgcn_mfma_f32_16x16x32_bf16(af[mt], bf[nt], acc[mt][nt], 0, 0, 0);
      __syncthreads();
    }
    #pragma unroll
    for (int mt=0;mt<2;++mt){
      #pragma unroll
      for (int nt=0;nt<2;++nt){
        int dd = wn*32 + nt*16 + mrow;
        #pragma unroll
        for (int r2=0;r2<4;++r2){
          int m = wm*32 + mt*16 + quad*4 + r2;
          agg_m[(size_t)(b*64 + m)*512 + h*64 + dd] = f2bf(geluf(acc[mt][nt][r2]));
        }
      }
    }
  }
}

// ---------------- means: partials (no atomics) + final (meanj fin + meanm merged) ----------------
__global__ __launch_bounds__(512) void meanj_part_k(const float* __restrict__ xo, float* scratchJ){
  int b = blockIdx.x, chunk = blockIdx.y, f = threadIdx.x;
  float s = 0.f;
  for (int r=0;r<128;++r){
    int row = b*1024 + chunk*128 + r;
    s += xo[(size_t)row*512 + f];
  }
  scratchJ[(b*8 + chunk)*512 + f] = s;
}
__global__ __launch_bounds__(512) void mean2_k(const float* __restrict__ scratchJ, float* __restrict__ out){
  int i = blockIdx.x*512 + threadIdx.x;   // 8192
  if (i < 4096){
    int b = i >> 9, f = i & 511;
    float s = 0.f;
    #pragma unroll
    for (int c=0;c<8;++c) s += scratchJ[(b*8+c)*512 + f];
    out[4456448 + i] = s * (1.f/1024.f);
  } else {
    int j = i - 4096;
    int b = j >> 9, f = j & 511;
    float s = 0.f;
    for (int r=0;r<64;++r) s += out[(size_t)TOPC + (size_t)(b*64+r)*512 + f];
    out[4460544 + j] = s * (1.f/64.f);
  }
}

extern "C" void kernel_launch(void* const* d_in, const int* in_sizes, int n_in,
                              void* d_out, int out_size, void* d_ws, size_t ws_size,
                              hipStream_t stream){
  const float* op_x      = (const float*)d_in[0];
  const float* machine_x = (const float*)d_in[1];
  const float* W_emb_op  = (const float*)d_in[2];
  const float* b_emb_op  = (const float*)d_in[3];
  const float* W_emb_m   = (const float*)d_in[4];
  const float* b_emb_m   = (const float*)d_in[5];
  const float* opn_w     = (const float*)d_in[6];
  const float* opn_b     = (const float*)d_in[7];
  const float* mn_w      = (const float*)d_in[8];
  const float* mn_b      = (const float*)d_in[9];
  const float* Wk        = (const float*)d_in[10];
  const float* bk        = (const float*)d_in[11];
  const float* Wq        = (const float*)d_in[12];
  const float* bq        = (const float*)d_in[13];
  const float* Wv        = (const float*)d_in[14];
  const float* bv        = (const float*)d_in[15];
  const float* A_rel     = (const float*)d_in[16];
  const float* M_rel     = (const float*)d_in[17];
  const float* p_rel     = (const float*)d_in[18];
  const float* W_out     = (const float*)d_in[19];
  const float* b_out     = (const float*)d_in[20];
  const float* skip      = (const float*)d_in[21];
  const float* ln_w      = (const float*)d_in[22];
  const float* ln_b      = (const float*)d_in[23];
  const int* s1          = (const int*)d_in[25];
  float* out = (float*)d_out;

  char* ws = (char*)d_ws;
  size_t off = 0;
  auto alloc = [&](size_t bytes)->void*{
    void* p = ws + off;
    off = (off + bytes + 255) & ~(size_t)255;
    return p;
  };
  float* pstat     = (float*)alloc(4096*4);
  float* scratchJ  = (float*)alloc(32768*4);
  float* Ct        = (float*)alloc((size_t)NMS*1024*4);
  float* Cn        = (float*)alloc((size_t)NOPS*64*4);
  float* S2f       = (float*)alloc((size_t)NMS*8*1024*4);
  u16*   W1        = (u16*)  alloc((size_t)NOPS*8*64*2);
  float* wpre      = (float*)alloc((size_t)NOPS*8*4);
  float* linv      = (float*)alloc((size_t)NOPS*8*4);
  float* x_op      = (float*)alloc((size_t)NOPS*512*4);
  u16*   x_op_bf   = (u16*)  alloc((size_t)NOPS*512*2);
  float* x_m       = (float*)alloc((size_t)NMS*512*4);
  u16*   x_m_bf    = (u16*)  alloc((size_t)NMS*512*2);
  u16*   qkv_op    = (u16*)  alloc((size_t)NOPS*CQ*2);   // 40MB; o_op (16MB f32) aliases it
  u16*   qkv_m     = (u16*)  alloc((size_t)NMS*CM*2);
  u16*   agg_op    = (u16*)  alloc((size_t)NOPS*512*2);
  u16*   agg_m     = (u16*)  alloc((size_t)NMS*512*2);
  u16*   Wc_op_t   = (u16*)  alloc((size_t)3*CQ*512*2);
  float* bias_op   = (float*)alloc((size_t)3*CQ*4);
  u16*   Wc_m_t    = (u16*)  alloc((size_t)3*CM*512*2);
  float* bias_m    = (float*)alloc((size_t)3*CM*4);
  u16*   Wout_t    = (u16*)  alloc((size_t)6*262144*2);
  float* o_op      = (float*)qkv_op;
  float* o_m       = (float*)qkv_m;
  float* pstat_m   = pstat + 2048;

  // setup (6 dispatches)
  cnt2_k<<<2048,256,0,stream>>>(s1, Ct, Cn);
  twout_k<<<dim3(6,8,8),256,0,stream>>>(W_out, Wout_t);
  tq_k<<<dim3(6,8,8),256,0,stream>>>(Wq, Wc_op_t, Wc_m_t);
  qb_k<<<12,256,0,stream>>>(bq, bias_op, bias_m);
  combine3_k<<<dim3(144,4),256,0,stream>>>(Wk, Wv, A_rel, M_rel, Wc_op_t, Wc_m_t);
  cbias_k<<<144,64,0,stream>>>(bk, bv, A_rel, M_rel, bias_op, bias_m);

  // embeddings + graph LN (2 dispatches)
  embed2_k<<<1152,256,0,stream>>>(op_x, W_emb_op, b_emb_op, x_op,
                                  machine_x, W_emb_m, b_emb_m, x_m, pstat, pstat_m);
  ln2_k<<<1152,256,0,stream>>>(x_op, x_op, x_op_bf, opn_w, opn_b,
                               x_m, x_m, x_m_bf, mn_w, mn_b, pstat, pstat_m);

  for (int l=0; l<3; ++l){
    int last = (l == 2);
    gemm2_k<<<1328,256,0,stream>>>(x_op_bf, Wc_op_t + (size_t)l*CQ*512, bias_op + l*CQ, qkv_op, CQ, 1, 20, 1280,
                                   x_m_bf, Wc_m_t + (size_t)l*CM*512, bias_m + l*CM, qkv_m, CM, 1, 12, 512);
    qk12_k<<<dim3(8,64,2),256,0,stream>>>(qkv_op, qkv_m, p_rel + l*24, Cn, W1, wpre, linv, S2f);
    agg12_k<<<576,256,0,stream>>>(W1, qkv_op, qkv_m, wpre, linv, agg_op, S2f, Ct, agg_m);
    gemm2_k<<<272,256,0,stream>>>(agg_op, Wout_t + (size_t)(l*2+0)*262144, nullptr, o_op, 512, 0, 4, 256,
                                  agg_m, Wout_t + (size_t)(l*2+1)*262144, nullptr, o_m, 512, 0, 4, 512);
    gate2_k<<<1152,256,0,stream>>>(o_op, x_op, b_out + (size_t)(l*2+0)*512, skip + l*2+0,
                                   o_m, x_m, b_out + (size_t)(l*2+1)*512, skip + l*2+1, pstat, pstat_m);
    ln2_k<<<1152,256,0,stream>>>(o_op, last ? out : x_op, x_op_bf, ln_w + l*512, ln_b + l*512,
                                 o_m, last ? (out + TOPC) : x_m, x_m_bf, ln_w + l*512, ln_b + l*512,
                                 pstat, pstat_m);
  }

  // means (2 dispatches); final features already written to `out` by last ln2
  meanj_part_k<<<dim3(8,8),512,0,stream>>>(out, scratchJ);
  mean2_k<<<16,512,0,stream>>>(scratchJ, out);
}

// Round 12
// 632.387 us; speedup vs baseline: 2.2946x; 2.2946x over previous
//
#include <hip/hip_runtime.h>

typedef unsigned short u16;
typedef __attribute__((ext_vector_type(4))) float floatx4;
typedef __attribute__((ext_vector_type(8))) short shortx8;
typedef __attribute__((ext_vector_type(4))) short shortx4;

#define NOPS 8192
#define NMS  512
#define CQ   2560   // op qkv cols: q | k0 | v0 | k2 | v2
#define CM   1536   // machine qkv cols: q | k1 | v1
#define NE2  65536
#define TOPC (NOPS*512)
#define TMC  (NMS*512)

__device__ __forceinline__ float bf2f(u16 u){ return __uint_as_float(((unsigned)u)<<16); }
__device__ __forceinline__ u16 f2bf(float f){
  unsigned u = __float_as_uint(f);
  u += 0x7FFFu + ((u>>16)&1u);
  return (u16)(u>>16);
}
__device__ __forceinline__ float wred(float v){
  #pragma unroll
  for (int o=32;o;o>>=1) v += __shfl_xor(v,o,64);
  return v;
}
__device__ __forceinline__ float wredmax(float v){
  #pragma unroll
  for (int o=32;o;o>>=1) v = fmaxf(v, __shfl_xor(v,o,64));
  return v;
}
__device__ __forceinline__ float geluf(float x){
  return 0.5f*x*(1.f+erff(x*0.70710678118654752f));
}
// block (s,s2) reduction -> one pair at pstat[slot]
__device__ __forceinline__ void block_stat_out2(float s, float s2, float* pstat, int slot){
  __shared__ float sb[8];
  s = wred(s); s2 = wred(s2);
  int wv = threadIdx.x >> 6;
  if ((threadIdx.x & 63) == 0){ sb[wv*2] = s; sb[wv*2+1] = s2; }
  __syncthreads();
  if (threadIdx.x == 0){
    float a = 0.f, b = 0.f;
    int nw = blockDim.x >> 6;
    for (int i=0;i<nw;++i){ a += sb[i*2]; b += sb[i*2+1]; }
    pstat[slot*2]   = a;
    pstat[slot*2+1] = b;
  }
}

// ---------------- edge multiplicity, no atomics / no pre-zero ----------------
__global__ __launch_bounds__(256) void cnt2_k(const int* __restrict__ s1, float* __restrict__ Ct,
                                              float* __restrict__ Cn){
  int idx = blockIdx.x*256 + threadIdx.x;      // 524288
  int n = idx >> 6, l = idx & 63;
  const int* row = s1 + n*8;
  int cnt = 0;
  #pragma unroll
  for (int j=0;j<8;++j) cnt += ((row[j] & 63) == l);
  float f = (float)cnt;
  Cn[(size_t)n*64 + l] = f;
  int b = n >> 10, nl = n & 1023;
  Ct[(size_t)((b<<6) + l)*1024 + nl] = f;
}

// ---------------- W_out: f32 [6][K][N] -> bf16 transposed [6][N][K] ----------------
__global__ __launch_bounds__(256) void twout_k(const float* __restrict__ src, u16* __restrict__ dst){
  __shared__ u16 t[64][65];
  int l = blockIdx.x, kb = blockIdx.y*64, nb = blockIdx.z*64;
  const float* s = src + (size_t)l*262144;
  u16* d = dst + (size_t)l*262144;
  int tx = threadIdx.x & 63, ty4 = threadIdx.x >> 6;
  #pragma unroll 4
  for (int p=0;p<16;++p){
    int k = ty4 + p*4;
    t[k][tx] = f2bf(s[(size_t)(kb+k)*512 + nb + tx]);
  }
  __syncthreads();
  #pragma unroll 4
  for (int p=0;p<16;++p){
    int n = ty4 + p*4;
    d[(size_t)(nb+n)*512 + kb + tx] = t[tx][n];
  }
}

// ---------------- Wq transpose into Wc rows 0..511 ----------------
__global__ __launch_bounds__(256) void tq_k(const float* __restrict__ Wq,
                                            u16* __restrict__ Wc_op_t, u16* __restrict__ Wc_m_t){
  __shared__ u16 tl[64][65];
  int blk = blockIdx.x;
  int l = blk >> 1, side = blk & 1;
  const float* s = Wq + (size_t)blk*262144;
  u16* d = side ? (Wc_m_t + (size_t)l*CM*512) : (Wc_op_t + (size_t)l*CQ*512);
  int kb = blockIdx.y*64, nb = blockIdx.z*64;
  int tx = threadIdx.x & 63, ty4 = threadIdx.x >> 6;
  #pragma unroll 4
  for (int p=0;p<16;++p){
    int k = ty4 + p*4;
    tl[k][tx] = f2bf(s[(size_t)(kb+k)*512 + nb + tx]);
  }
  __syncthreads();
  #pragma unroll 4
  for (int p=0;p<16;++p){
    int n = ty4 + p*4;
    d[(size_t)(nb+n)*512 + kb + tx] = tl[tx][n];
  }
}

// ---------------- q biases ----------------
__global__ void qb_k(const float* __restrict__ bq, float* bias_op, float* bias_m){
  int i = blockIdx.x*blockDim.x + threadIdx.x;
  if (i >= 3072) return;
  int l = i >> 10, side = (i >> 9) & 1, f = i & 511;
  float v = bq[(l*2+side)*512 + f];
  if (side==0) bias_op[l*CQ + f] = v; else bias_m[l*CM + f] = v;
}

// ---------------- relation combine via MFMA: grid (144,4) ----------------
__global__ __launch_bounds__(256) void combine3_k(const float* __restrict__ Wk, const float* __restrict__ Wv,
                                                  const float* __restrict__ Ar, const float* __restrict__ Mr,
                                                  u16* __restrict__ Wc_op_t, u16* __restrict__ Wc_m_t){
  __shared__ u16 As[64*72];
  __shared__ u16 Bs[128*72];
  int gx = blockIdx.x;
  int l = gx/48; int rem = gx - l*48; int s = rem >> 3; int h = rem & 7;
  int side = (s < 4) ? 0 : 1;
  int r = (s < 4) ? (s+1) : (s-3);
  int useK = side==0 ? (s==0 || s==2) : (s==4);
  int rel  = side==0 ? ((s<2)?0:2) : 1;
  const float* W   = (useK ? Wk : Wv) + (size_t)(l*2+side)*262144;
  const float* Rel = (useK ? Ar : Mr) + ((size_t)(l*3+rel)*8 + h)*4096;
  int h64 = h*64;
  u16* Wt = side ? (Wc_m_t + (size_t)l*CM*512) : (Wc_op_t + (size_t)l*CQ*512);
  int rbase = r*512 + h64;
  int cc0 = blockIdx.y * 128;
  int tid = threadIdx.x, lane = tid & 63, wave = tid >> 6;
  {
    int d = tid >> 2, e0 = (tid & 3) * 16;
    #pragma unroll
    for (int j=0;j<16;++j) As[(e0+j)*72 + d] = f2bf(Rel[d*64 + e0 + j]);
  }
  {
    int ccl = tid >> 1, d0 = (tid & 1) * 32;
    const float* src = W + (size_t)(cc0+ccl)*512 + h64 + d0;
    #pragma unroll
    for (int j=0;j<32;j+=4){
      floatx4 v = *(const floatx4*)(src + j);
      shortx4 sv;
      #pragma unroll
      for (int e=0;e<4;++e) sv[e] = (short)f2bf(v[e]);
      *(shortx4*)(Bs + ccl*72 + d0 + j) = sv;
    }
  }
  __syncthreads();
  int wm = wave & 1, wn = wave >> 1;
  int mrow = lane & 15, quad = lane >> 4;
  floatx4 acc[2][4];
  #pragma unroll
  for (int a=0;a<2;++a)
    #pragma unroll
    for (int b=0;b<4;++b) acc[a][b] = (floatx4){0.f,0.f,0.f,0.f};
  #pragma unroll
  for (int ks=0; ks<2; ++ks){
    shortx8 af[2], bf[4];
    #pragma unroll
    for (int mt=0;mt<2;++mt) af[mt] = *(const shortx8*)(As + (wm*32 + mt*16 + mrow)*72 + ks*32 + quad*8);
    #pragma unroll
    for (int nt=0;nt<4;++nt) bf[nt] = *(const shortx8*)(Bs + (wn*64 + nt*16 + mrow)*72 + ks*32 + quad*8);
    #pragma unroll
    for (int mt=0;mt<2;++mt)
      #pragma unroll
      for (int nt=0;nt<4;++nt)
        acc[mt][nt] = __builtin_amdgcn_mfma_f32_16x16x32_bf16(af[mt], bf[nt], acc[mt][nt], 0, 0, 0);
  }
  #pragma unroll
  for (int mt=0;mt<2;++mt){
    #pragma unroll
    for (int nt=0;nt<4;++nt){
      int ccl = wn*64 + nt*16 + mrow;
      #pragma unroll
      for (int r2=0;r2<4;++r2){
        int e = wm*32 + mt*16 + quad*4 + r2;
        Wt[(size_t)(rbase + e)*512 + cc0 + ccl] = f2bf(acc[mt][nt][r2]);
      }
    }
  }
}
// bias row of the combine (cc==512)
__global__ void cbias_k(const float* __restrict__ bk, const float* __restrict__ bv,
                        const float* __restrict__ Ar, const float* __restrict__ Mr,
                        float* bias_op, float* bias_m){
  int gx = blockIdx.x; int e = threadIdx.x;
  int l = gx/48; int rem = gx - l*48; int s = rem >> 3; int h = rem & 7;
  int side = (s < 4) ? 0 : 1;
  int r = (s < 4) ? (s+1) : (s-3);
  int useK = side==0 ? (s==0 || s==2) : (s==4);
  int rel  = side==0 ? ((s<2)?0:2) : 1;
  const float* bb  = (useK ? bk : bv) + (size_t)(l*2+side)*512 + h*64;
  const float* Rel = (useK ? Ar : Mr) + ((size_t)(l*3+rel)*8 + h)*4096;
  float acc = 0.f;
  for (int d=0; d<64; ++d) acc += bb[d]*Rel[d*64 + e];
  float* bias = side ? (bias_m + l*CM) : (bias_op + l*CQ);
  bias[r*512 + h*64 + e] = acc;
}

// ---------------- merged embedding (op+m) + per-block LN partials ----------------
__global__ __launch_bounds__(256) void embed2_k(const float* __restrict__ Xop, const float* __restrict__ Wop,
                                                const float* __restrict__ bop, float* __restrict__ Yop,
                                                const float* __restrict__ Xm, const float* __restrict__ Wm,
                                                const float* __restrict__ bm_, float* __restrict__ Ym,
                                                float* pstat, float* pstat_m){
  int bid = blockIdx.x;
  const float *X, *W, *bias; float *Y, *ps; int K, total, nb, lb;
  if (bid < 1024){ X=Xop; W=Wop; bias=bop; Y=Yop; ps=pstat;   K=16; total=TOPC; nb=1024; lb=bid; }
  else           { X=Xm;  W=Wm;  bias=bm_; Y=Ym;  ps=pstat_m; K=8;  total=TMC;  nb=128;  lb=bid-1024; }
  float s = 0.f, s2 = 0.f;
  for (int idx = lb*256 + threadIdx.x; idx < total; idx += nb*256){
    int n = idx >> 9, f = idx & 511;
    float v = bias[f];
    for (int c=0;c<K;++c) v += X[n*K+c] * W[c*512+f];
    Y[idx] = v;
    s += v; s2 += v*v;
  }
  block_stat_out2(s, s2, ps, lb);
}

// ---------------- merged graph-LN apply (op+m), with in-block pstat reduction ----------------
__global__ __launch_bounds__(256) void ln2_k(const float* __restrict__ src_op, float* __restrict__ dst_op,
                                             u16* __restrict__ dbf_op, const float* __restrict__ w_op,
                                             const float* __restrict__ b_op,
                                             const float* __restrict__ src_m, float* __restrict__ dst_m,
                                             u16* __restrict__ dbf_m, const float* __restrict__ w_m,
                                             const float* __restrict__ b_m,
                                             const float* __restrict__ pstat, const float* __restrict__ pstat_m){
  int bid = blockIdx.x;
  const float *src, *w, *b, *ps; float* dst; u16* dbf; int total4, nb, lb, nblk; float inv_n;
  if (bid < 1024){ src=src_op; dst=dst_op; dbf=dbf_op; w=w_op; b=b_op; ps=pstat;
                   total4=TOPC/4; nb=1024; lb=bid; nblk=1024; inv_n=1.f/TOPC; }
  else           { src=src_m;  dst=dst_m;  dbf=dbf_m;  w=w_m;  b=b_m;  ps=pstat_m;
                   total4=TMC/4;  nb=128;  lb=bid-1024; nblk=128; inv_n=1.f/TMC; }
  __shared__ float sb[8];
  __shared__ float mr[2];
  float s = 0.f, s2 = 0.f;
  for (int i = threadIdx.x; i < nblk; i += 256){ s += ps[2*i]; s2 += ps[2*i+1]; }
  s = wred(s); s2 = wred(s2);
  int wv = threadIdx.x >> 6;
  if ((threadIdx.x & 63) == 0){ sb[wv*2] = s; sb[wv*2+1] = s2; }
  __syncthreads();
  if (threadIdx.x == 0){
    float a = 0.f, bsum = 0.f;
    for (int i=0;i<4;++i){ a += sb[i*2]; bsum += sb[i*2+1]; }
    float mean = a * inv_n;
    float var  = fmaxf(bsum * inv_n - mean*mean, 0.f);
    mr[0] = mean;
    mr[1] = 1.f/(sqrtf(var) + 1e-5f);
  }
  __syncthreads();
  float mean = mr[0], rinv = mr[1];
  const floatx4* s4 = (const floatx4*)src;
  floatx4* d4 = (floatx4*)dst;
  shortx4* db4 = (shortx4*)dbf;
  const floatx4* w4 = (const floatx4*)w;
  const floatx4* b4 = (const floatx4*)b;
  for (int i = lb*256 + threadIdx.x; i < total4; i += nb*256){
    int f = i & 127;
    floatx4 v = s4[i], wv2 = w4[f], bv = b4[f];
    shortx4 sv;
    #pragma unroll
    for (int e=0;e<4;++e){ v[e] = (v[e]-mean)*rinv*wv2[e] + bv[e]; sv[e] = (short)f2bf(v[e]); }
    d4[i] = v;
    db4[i] = sv;
  }
}

// ---------------- merged gated residual (op+m) + per-block LN partials ----------------
__global__ __launch_bounds__(256) void gate2_k(float* __restrict__ y_op, const float* __restrict__ x_op,
                                               const float* __restrict__ bo_op, const float* __restrict__ sk_op,
                                               float* __restrict__ y_m, const float* __restrict__ x_m,
                                               const float* __restrict__ bo_m, const float* __restrict__ sk_m,
                                               float* pstat, float* pstat_m){
  int bid = blockIdx.x;
  float *y, *ps; const float *x, *bo, *sk; int total4, nb, lb;
  if (bid < 1024){ y=y_op; x=x_op; bo=bo_op; sk=sk_op; ps=pstat;   total4=TOPC/4; nb=1024; lb=bid; }
  else           { y=y_m;  x=x_m;  bo=bo_m;  sk=sk_m;  ps=pstat_m; total4=TMC/4;  nb=128;  lb=bid-1024; }
  float g = 1.f/(1.f+expf(-(*sk)));
  floatx4* y4 = (floatx4*)y;
  const floatx4* x4 = (const floatx4*)x;
  const floatx4* b4 = (const floatx4*)bo;
  float s = 0.f, s2 = 0.f;
  for (int i = lb*256 + threadIdx.x; i < total4; i += nb*256){
    floatx4 yv = y4[i], xv = x4[i], bv = b4[i & 127];
    #pragma unroll
    for (int e=0;e<4;++e){
      float o = g*(yv[e]+bv[e]) + (2.f-g)*xv[e];
      yv[e] = o;
      s += o; s2 += o*o;
    }
    y4[i] = yv;
  }
  block_stat_out2(s, s2, ps, lb);
}

// ---------------- m97-style GEMM core + merged dual-GEMM kernel ----------------
__device__ __forceinline__ void gemm_core(u16* As, u16* Bs, const u16* __restrict__ A,
                                          const u16* __restrict__ Bt, const float* __restrict__ bias,
                                          void* __restrict__ Cp, int N, int K, int out_bf16,
                                          int bx, int by){
  const int tid = threadIdx.x;
  const int lane = tid & 63, wave = tid >> 6;
  const int bm = by * 128, bn = bx * 128;
  const int wm = wave & 1, wn = wave >> 1;
  const int mrow = lane & 15, quad = lane >> 4;
  const u16* Ab = A + (size_t)bm*K;
  const u16* Bb = Bt + (size_t)bn*K;
  floatx4 acc[4][4];
  #pragma unroll
  for (int a=0;a<4;++a)
    #pragma unroll
    for (int b=0;b<4;++b) acc[a][b] = (floatx4){0.f,0.f,0.f,0.f};
  const int r0 = tid >> 2, c0 = (tid & 3) * 8;
  const int r1 = (tid+256) >> 2, c1 = ((tid+256) & 3) * 8;
  const int lds0 = wave*512;
  const int lds1 = wave*512 + 2048;
  for (int k0 = 0; k0 < K; k0 += 32){
    __builtin_amdgcn_global_load_lds((const __attribute__((address_space(1))) void*)(Ab + (size_t)r0*K + k0 + c0),
                                     (__attribute__((address_space(3))) void*)(As + lds0), 16, 0, 0);
    __builtin_amdgcn_global_load_lds((const __attribute__((address_space(1))) void*)(Ab + (size_t)r1*K + k0 + c1),
                                     (__attribute__((address_space(3))) void*)(As + lds1), 16, 0, 0);
    __builtin_amdgcn_global_load_lds((const __attribute__((address_space(1))) void*)(Bb + (size_t)r0*K + k0 + c0),
                                     (__attribute__((address_space(3))) void*)(Bs + lds0), 16, 0, 0);
    __builtin_amdgcn_global_load_lds((const __attribute__((address_space(1))) void*)(Bb + (size_t)r1*K + k0 + c1),
                                     (__attribute__((address_space(3))) void*)(Bs + lds1), 16, 0, 0);
    __syncthreads();
    shortx8 af[4], bf[4];
    #pragma unroll
    for (int mt=0;mt<4;++mt) af[mt] = *(const shortx8*)(As + (wm*64 + mt*16 + mrow)*32 + quad*8);
    #pragma unroll
    for (int nt=0;nt<4;++nt) bf[nt] = *(const shortx8*)(Bs + (wn*64 + nt*16 + mrow)*32 + quad*8);
    #pragma unroll
    for (int mt=0;mt<4;++mt)
      #pragma unroll
      for (int nt=0;nt<4;++nt)
        acc[mt][nt] = __builtin_amdgcn_mfma_f32_16x16x32_bf16(af[mt], bf[nt], acc[mt][nt], 0, 0, 0);
    __syncthreads();
  }
  #pragma unroll
  for (int mt=0;mt<4;++mt){
    #pragma unroll
    for (int nt=0;nt<4;++nt){
      int col = bn + wn*64 + nt*16 + mrow;
      float bval = bias ? bias[col] : 0.f;
      #pragma unroll
      for (int r2=0;r2<4;++r2){
        int row = bm + wm*64 + mt*16 + quad*4 + r2;
        float v = acc[mt][nt][r2] + bval;
        if (out_bf16) ((u16*)Cp)[(size_t)row*N + col] = f2bf(v);
        else          ((float*)Cp)[(size_t)row*N + col] = v;
      }
    }
  }
}
__global__ __launch_bounds__(256) void gemm2_k(const u16* A1, const u16* B1, const float* bias1, void* C1,
                                               int N1, int ob1, int ntx1, int nblk1,
                                               const u16* A2, const u16* B2, const float* bias2, void* C2,
                                               int N2, int ob2, int ntx2, int K){
  __shared__ u16 As[128*32];
  __shared__ u16 Bs[128*32];
  int id = blockIdx.x;
  if (id < nblk1) gemm_core(As, Bs, A1, B1, bias1, C1, N1, K, ob1, id % ntx1, id / ntx1);
  else { int j = id - nblk1; gemm_core(As, Bs, A2, B2, bias2, C2, N2, K, ob2, j % ntx2, j / ntx2); }
}

// ---------------- merged score GEMMs + fused op-softmax ----------------
// z=0: S1 = q_op x k1^T -> in-block masked softmax (+precedes) -> W1, wpre, linv
// z=1: S2 = q_m x k2^T -> S2f (softmax in msoftm_k)
__global__ __launch_bounds__(256) void qk12_k(const u16* __restrict__ qkv_op, const u16* __restrict__ qkv_m,
                                              const float* __restrict__ prel, const float* __restrict__ Cn,
                                              u16* __restrict__ W1, float* __restrict__ wpre,
                                              float* __restrict__ linv, float* __restrict__ S2f){
  __shared__ __align__(16) char smem[36864];
  u16* As = (u16*)smem;             // 128*72
  u16* Bs = As + 128*72;            // 128*72
  float* Sbuf = (float*)smem;       // 128*65 floats, aliases staging after barrier
  int bh = blockIdx.y; int b = bh >> 3, h = bh & 7;
  int n0 = blockIdx.x * 128;
  int tid = threadIdx.x, lane = tid & 63, wave = tid >> 6;
  int mrow = lane & 15, quad = lane >> 4;
  if (blockIdx.z == 0){
    int wm = wave & 1, wn = wave >> 1;
    float p1 = prel[8 + h] * 0.125f;
    {
      int row = tid >> 1, col = (tid & 1) * 32;
      const u16* src = qkv_op + (size_t)(b*1024 + n0 + row)*CQ + h*64 + col;
      #pragma unroll
      for (int e=0;e<4;++e) *(shortx8*)(As + row*72 + col + e*8) = *(const shortx8*)(src + e*8);
    }
    {
      int row = tid >> 2, col = (tid & 3) * 16;
      const u16* src = qkv_m + (size_t)(b*64 + row)*CM + 512 + h*64 + col;
      *(shortx8*)(Bs + row*72 + col)     = *(const shortx8*)(src);
      *(shortx8*)(Bs + row*72 + col + 8) = *(const shortx8*)(src + 8);
    }
    __syncthreads();
    floatx4 acc[4][2];
    #pragma unroll
    for (int a=0;a<4;++a){ acc[a][0] = (floatx4){0,0,0,0}; acc[a][1] = (floatx4){0,0,0,0}; }
    #pragma unroll
    for (int ks=0; ks<2; ++ks){
      shortx8 af[4], bf[2];
      #pragma unroll
      for (int mt=0;mt<4;++mt) af[mt] = *(const shortx8*)(As + (wm*64 + mt*16 + mrow)*72 + ks*32 + quad*8);
      #pragma unroll
      for (int nt=0;nt<2;++nt) bf[nt] = *(const shortx8*)(Bs + (wn*32 + nt*16 + mrow)*72 + ks*32 + quad*8);
      #pragma unroll
      for (int mt=0;mt<4;++mt)
        #pragma unroll
        for (int nt=0;nt<2;++nt)
          acc[mt][nt] = __builtin_amdgcn_mfma_f32_16x16x32_bf16(af[mt], bf[nt], acc[mt][nt], 0, 0, 0);
    }
    __syncthreads();   // staging reads done; reuse smem for scores
    #pragma unroll
    for (int mt=0;mt<4;++mt){
      #pragma unroll
      for (int nt=0;nt<2;++nt){
        int m = wn*32 + nt*16 + mrow;
        #pragma unroll
        for (int r2=0;r2<4;++r2){
          int nl = wm*64 + mt*16 + quad*4 + r2;
          Sbuf[nl*65 + m] = acc[mt][nt][r2] * p1;
        }
      }
    }
    __syncthreads();
    if (tid < 128){
      int n_g = b*1024 + n0 + tid;
      int nl  = n0 + tid;             // local op index in graph
      float sp = -1e30f;
      if (nl > 0){
        float p0 = prel[h] * 0.125f;
        const u16* qp = qkv_op + (size_t)n_g*CQ + h*64;
        const u16* kp = qkv_op + (size_t)(n_g-1)*CQ + 512 + h*64;
        float d = 0.f;
        #pragma unroll
        for (int j=0;j<8;++j){
          shortx8 qa = *(const shortx8*)(qp + j*8);
          shortx8 ka = *(const shortx8*)(kp + j*8);
          #pragma unroll
          for (int e=0;e<8;++e) d += bf2f((u16)qa[e])*bf2f((u16)ka[e]);
        }
        sp = d * p0;
      }
      const float* crow = Cn + (size_t)n_g*64;
      float mx = sp;
      #pragma unroll
      for (int m=0;m<64;++m){
        if (crow[m] > 0.f) mx = fmaxf(mx, Sbuf[tid*65 + m]);
      }
      float L = 0.f;
      u16* wrow = W1 + ((size_t)n_g*8 + h)*64;
      #pragma unroll
      for (int m0=0;m0<64;m0+=4){
        shortx4 pv;
        #pragma unroll
        for (int e=0;e<4;++e){
          float c = crow[m0+e];
          float w = (c > 0.f) ? c*expf(Sbuf[tid*65 + m0+e]-mx) : 0.f;
          L += w;
          pv[e] = (short)f2bf(w);
        }
        *(shortx4*)(wrow + m0) = pv;
      }
      float ep = (nl > 0) ? expf(sp - mx) : 0.f;
      L += ep;
      wpre[(size_t)n_g*8 + h] = ep;
      linv[(size_t)n_g*8 + h] = 1.f/(L + 1e-16f);
    }
  } else {
    float p2 = prel[16 + h] * 0.125f;
    {
      int row = tid >> 2, col = (tid & 3) * 16;
      const u16* src = qkv_m + (size_t)(b*64+row)*CM + h*64 + col;
      *(shortx8*)(As + row*72 + col)     = *(const shortx8*)(src);
      *(shortx8*)(As + row*72 + col + 8) = *(const shortx8*)(src + 8);
    }
    {
      int row = tid >> 1, col = (tid & 1) * 32;
      const u16* src = qkv_op + (size_t)(b*1024 + n0 + row)*CQ + 1536 + h*64 + col;
      #pragma unroll
      for (int e=0;e<4;++e) *(shortx8*)(Bs + row*72 + col + e*8) = *(const shortx8*)(src + e*8);
    }
    __syncthreads();
    floatx4 acc[4][2];
    #pragma unroll
    for (int a=0;a<4;++a){ acc[a][0] = (floatx4){0,0,0,0}; acc[a][1] = (floatx4){0,0,0,0}; }
    #pragma unroll
    for (int ks=0; ks<2; ++ks){
      shortx8 af[4], bf[2];
      #pragma unroll
      for (int mt=0;mt<4;++mt) af[mt] = *(const shortx8*)(As + (mt*16 + mrow)*72 + ks*32 + quad*8);
      #pragma unroll
      for (int nt=0;nt<2;++nt) bf[nt] = *(const shortx8*)(Bs + (wave*32 + nt*16 + mrow)*72 + ks*32 + quad*8);
      #pragma unroll
      for (int mt=0;mt<4;++mt)
        #pragma unroll
        for (int nt=0;nt<2;++nt)
          acc[mt][nt] = __builtin_amdgcn_mfma_f32_16x16x32_bf16(af[mt], bf[nt], acc[mt][nt], 0, 0, 0);
    }
    #pragma unroll
    for (int mt=0;mt<4;++mt){
      #pragma unroll
      for (int nt=0;nt<2;++nt){
        int n = n0 + wave*32 + nt*16 + mrow;
        #pragma unroll
        for (int r2=0;r2<4;++r2){
          int m = mt*16 + quad*4 + r2;
          S2f[((size_t)(b*64 + m)*8 + h)*1024 + n] = acc[mt][nt][r2] * p2;
        }
      }
    }
  }
}

// ---------------- machine softmax (count-weighted), wide: 512 blocks x 512 threads ----------------
__global__ __launch_bounds__(512) void msoftm_k(const float* __restrict__ S2f, const float* __restrict__ Ct,
                                                u16* __restrict__ W2){
  int m = blockIdx.x;
  int h = threadIdx.x >> 6, d = threadIdx.x & 63;
  const float* srow = S2f + ((size_t)m*8 + h)*1024;
  const float* crow = Ct + (size_t)m*1024;
  float s[16], c[16];
  #pragma unroll
  for (int it=0; it<16; ++it){ s[it] = srow[it*64 + d]; c[it] = crow[it*64 + d]; }
  float mx = -1e30f;
  #pragma unroll
  for (int it=0; it<16; ++it) if (c[it] > 0.f) mx = fmaxf(mx, s[it]);
  mx = wredmax(mx);
  float e[16], L = 0.f;
  #pragma unroll
  for (int it=0; it<16; ++it){
    e[it] = (c[it] > 0.f) ? c[it]*expf(s[it]-mx) : 0.f;
    L += e[it];
  }
  L = wred(L);
  float inv = 1.f/(L + 1e-16f);
  u16* wrow = W2 + ((size_t)m*8 + h)*1024;
  #pragma unroll
  for (int it=0; it<16; ++it) wrow[it*64 + d] = f2bf(e[it]*inv);
}

// ---------------- merged agg GEMMs: [0,512) op-side; [512,576) machine-side (reads W2) ----------------
__global__ __launch_bounds__(256) void agg12_k(const u16* __restrict__ W1, const u16* __restrict__ qkv_op,
                                               const u16* __restrict__ qkv_m, const float* __restrict__ wpre,
                                               const float* __restrict__ linv, u16* __restrict__ agg_op,
                                               const u16* __restrict__ W2, u16* __restrict__ agg_m){
  __shared__ u16 As[128*72];
  __shared__ u16 Bs[64*72];
  int bid = blockIdx.x;
  int tid = threadIdx.x, lane = tid & 63, wave = tid >> 6;
  int wm = wave & 1, wn = wave >> 1;
  int mrow = lane & 15, quad = lane >> 4;
  if (bid < 512){
    int bh = bid >> 3; int b = bh >> 3, h = bh & 7;
    int n0 = (bid & 7) * 128;
    {
      int row = tid >> 1, col = (tid & 1) * 32;
      const u16* src = W1 + ((size_t)(b*1024 + n0 + row)*8 + h)*64 + col;
      #pragma unroll
      for (int e=0;e<4;++e) *(shortx8*)(As + row*72 + col + e*8) = *(const shortx8*)(src + e*8);
    }
    {
      int m = tid >> 2, dcol = (tid & 3) * 16;
      const u16* src = qkv_m + (size_t)(b*64 + m)*CM + 1024 + h*64 + dcol;
      shortx8 v0 = *(const shortx8*)(src);
      shortx8 v1 = *(const shortx8*)(src + 8);
      #pragma unroll
      for (int e=0;e<8;++e){ Bs[(dcol+e)*72 + m] = (u16)v0[e]; Bs[(dcol+8+e)*72 + m] = (u16)v1[e]; }
    }
    __syncthreads();
    floatx4 acc[4][2];
    #pragma unroll
    for (int a=0;a<4;++a){ acc[a][0] = (floatx4){0,0,0,0}; acc[a][1] = (floatx4){0,0,0,0}; }
    #pragma unroll
    for (int ks=0; ks<2; ++ks){
      shortx8 af[4], bf[2];
      #pragma unroll
      for (int mt=0;mt<4;++mt) af[mt] = *(const shortx8*)(As + (wm*64 + mt*16 + mrow)*72 + ks*32 + quad*8);
      #pragma unroll
      for (int nt=0;nt<2;++nt) bf[nt] = *(const shortx8*)(Bs + (wn*32 + nt*16 + mrow)*72 + ks*32 + quad*8);
      #pragma unroll
      for (int mt=0;mt<4;++mt)
        #pragma unroll
        for (int nt=0;nt<2;++nt)
          acc[mt][nt] = __builtin_amdgcn_mfma_f32_16x16x32_bf16(af[mt], bf[nt], acc[mt][nt], 0, 0, 0);
    }
    #pragma unroll
    for (int mt=0;mt<4;++mt){
      #pragma unroll
      for (int nt=0;nt<2;++nt){
        int d = wn*32 + nt*16 + mrow;
        #pragma unroll
        for (int r2=0;r2<4;++r2){
          int n = n0 + wm*64 + mt*16 + quad*4 + r2;
          size_t ng = (size_t)b*1024 + n;
          size_t ih = ng*8 + h;
          float v = acc[mt][nt][r2];
          if ((n & 1023) > 0) v += wpre[ih] * bf2f(qkv_op[(ng-1)*CQ + 1024 + h*64 + d]);
          v *= linv[ih];
          agg_op[ng*512 + h*64 + d] = f2bf(geluf(v));
        }
      }
    }
  } else {
    int bh = bid - 512; int b = bh >> 3, h = bh & 7;
    floatx4 acc[2][2];
    acc[0][0]=(floatx4){0,0,0,0}; acc[0][1]=(floatx4){0,0,0,0};
    acc[1][0]=(floatx4){0,0,0,0}; acc[1][1]=(floatx4){0,0,0,0};
    const int arow = tid >> 2, acol = (tid & 3) * 8;
    const int nrow = tid >> 3, dcol = (tid & 7) * 8;
    for (int ks = 0; ks < 32; ++ks){
      int nn0 = ks*32;
      *(shortx8*)(As + arow*40 + acol) =
          *(const shortx8*)(W2 + ((size_t)(b*64 + arow)*8 + h)*1024 + nn0 + acol);
      shortx8 vv = *(const shortx8*)(qkv_op + (size_t)(b*1024 + nn0 + nrow)*CQ + 2048 + h*64 + dcol);
      #pragma unroll
      for (int e=0;e<8;++e) Bs[(dcol+e)*40 + nrow] = (u16)vv[e];
      __syncthreads();
      shortx8 af[2], bf[2];
      #pragma unroll
      for (int mt=0;mt<2;++mt) af[mt] = *(const shortx8*)(As + (wm*32 + mt*16 + mrow)*40 + quad*8);
      #pragma unroll
      for (int nt=0;nt<2;++nt) bf[nt] = *(const shortx8*)(Bs + (wn*32 + nt*16 + mrow)*40 + quad*8);
      #pragma unroll
      for (int mt=0;mt<2;++mt)
        #pragma unroll
        for (int nt=0;nt<2;++nt)
          acc[mt][nt] = __builtin_amdgcn_mfma_f32_16x16x32_bf16(af[mt], bf[nt], acc[mt][nt], 0, 0, 0);
      __syncthreads();
    }
    #pragma unroll
    for (int mt=0;mt<2;++mt){
      #pragma unroll
      for (int nt=0;nt<2;++nt){
        int dd = wn*32 + nt*16 + mrow;
        #pragma unroll
        for (int r2=0;r2<4;++r2){
          int m = wm*32 + mt*16 + quad*4 + r2;
          agg_m[(size_t)(b*64 + m)*512 + h*64 + dd] = f2bf(geluf(acc[mt][nt][r2]));
        }
      }
    }
  }
}

// ---------------- means: partials (no atomics) + final merged ----------------
__global__ __launch_bounds__(512) void meanj_part_k(const float* __restrict__ xo, float* scratchJ){
  int b = blockIdx.x, chunk = blockIdx.y, f = threadIdx.x;
  float s = 0.f;
  for (int r=0;r<128;++r){
    int row = b*1024 + chunk*128 + r;
    s += xo[(size_t)row*512 + f];
  }
  scratchJ[(b*8 + chunk)*512 + f] = s;
}
__global__ __launch_bounds__(512) void mean2_k(const float* __restrict__ scratchJ, float* __restrict__ out){
  int i = blockIdx.x*512 + threadIdx.x;   // 8192
  if (i < 4096){
    int b = i >> 9, f = i & 511;
    float s = 0.f;
    #pragma unroll
    for (int c=0;c<8;++c) s += scratchJ[(b*8+c)*512 + f];
    out[4456448 + i] = s * (1.f/1024.f);
  } else {
    int j = i - 4096;
    int b = j >> 9, f = j & 511;
    float s = 0.f;
    for (int r=0;r<64;++r) s += out[(size_t)TOPC + (size_t)(b*64+r)*512 + f];
    out[4460544 + j] = s * (1.f/64.f);
  }
}

extern "C" void kernel_launch(void* const* d_in, const int* in_sizes, int n_in,
                              void* d_out, int out_size, void* d_ws, size_t ws_size,
                              hipStream_t stream){
  const float* op_x      = (const float*)d_in[0];
  const float* machine_x = (const float*)d_in[1];
  const float* W_emb_op  = (const float*)d_in[2];
  const float* b_emb_op  = (const float*)d_in[3];
  const float* W_emb_m   = (const float*)d_in[4];
  const float* b_emb_m   = (const float*)d_in[5];
  const float* opn_w     = (const float*)d_in[6];
  const float* opn_b     = (const float*)d_in[7];
  const float* mn_w      = (const float*)d_in[8];
  const float* mn_b      = (const float*)d_in[9];
  const float* Wk        = (const float*)d_in[10];
  const float* bk        = (const float*)d_in[11];
  const float* Wq        = (const float*)d_in[12];
  const float* bq        = (const float*)d_in[13];
  const float* Wv        = (const float*)d_in[14];
  const float* bv        = (const float*)d_in[15];
  const float* A_rel     = (const float*)d_in[16];
  const float* M_rel     = (const float*)d_in[17];
  const float* p_rel     = (const float*)d_in[18];
  const float* W_out     = (const float*)d_in[19];
  const float* b_out     = (const float*)d_in[20];
  const float* skip      = (const float*)d_in[21];
  const float* ln_w      = (const float*)d_in[22];
  const float* ln_b      = (const float*)d_in[23];
  const int* s1          = (const int*)d_in[25];
  float* out = (float*)d_out;

  char* ws = (char*)d_ws;
  size_t off = 0;
  auto alloc = [&](size_t bytes)->void*{
    void* p = ws + off;
    off = (off + bytes + 255) & ~(size_t)255;
    return p;
  };
  float* pstat     = (float*)alloc(4096*4);
  float* scratchJ  = (float*)alloc(32768*4);
  float* Ct        = (float*)alloc((size_t)NMS*1024*4);
  float* Cn        = (float*)alloc((size_t)NOPS*64*4);
  float* S2f       = (float*)alloc((size_t)NMS*8*1024*4);
  u16*   W2        = (u16*)  alloc((size_t)NMS*8*1024*2);
  u16*   W1        = (u16*)  alloc((size_t)NOPS*8*64*2);
  float* wpre      = (float*)alloc((size_t)NOPS*8*4);
  float* linv      = (float*)alloc((size_t)NOPS*8*4);
  float* x_op      = (float*)alloc((size_t)NOPS*512*4);
  u16*   x_op_bf   = (u16*)  alloc((size_t)NOPS*512*2);
  float* x_m       = (float*)alloc((size_t)NMS*512*4);
  u16*   x_m_bf    = (u16*)  alloc((size_t)NMS*512*2);
  u16*   qkv_op    = (u16*)  alloc((size_t)NOPS*CQ*2);   // 40MB; o_op (16MB f32) aliases it
  u16*   qkv_m     = (u16*)  alloc((size_t)NMS*CM*2);
  u16*   agg_op    = (u16*)  alloc((size_t)NOPS*512*2);
  u16*   agg_m     = (u16*)  alloc((size_t)NMS*512*2);
  u16*   Wc_op_t   = (u16*)  alloc((size_t)3*CQ*512*2);
  float* bias_op   = (float*)alloc((size_t)3*CQ*4);
  u16*   Wc_m_t    = (u16*)  alloc((size_t)3*CM*512*2);
  float* bias_m    = (float*)alloc((size_t)3*CM*4);
  u16*   Wout_t    = (u16*)  alloc((size_t)6*262144*2);
  float* o_op      = (float*)qkv_op;
  float* o_m       = (float*)qkv_m;
  float* pstat_m   = pstat + 2048;

  // setup (6 dispatches)
  cnt2_k<<<2048,256,0,stream>>>(s1, Ct, Cn);
  twout_k<<<dim3(6,8,8),256,0,stream>>>(W_out, Wout_t);
  tq_k<<<dim3(6,8,8),256,0,stream>>>(Wq, Wc_op_t, Wc_m_t);
  qb_k<<<12,256,0,stream>>>(bq, bias_op, bias_m);
  combine3_k<<<dim3(144,4),256,0,stream>>>(Wk, Wv, A_rel, M_rel, Wc_op_t, Wc_m_t);
  cbias_k<<<144,64,0,stream>>>(bk, bv, A_rel, M_rel, bias_op, bias_m);

  // embeddings + graph LN (2 dispatches)
  embed2_k<<<1152,256,0,stream>>>(op_x, W_emb_op, b_emb_op, x_op,
                                  machine_x, W_emb_m, b_emb_m, x_m, pstat, pstat_m);
  ln2_k<<<1152,256,0,stream>>>(x_op, x_op, x_op_bf, opn_w, opn_b,
                               x_m, x_m, x_m_bf, mn_w, mn_b, pstat, pstat_m);

  for (int l=0; l<3; ++l){
    int last = (l == 2);
    gemm2_k<<<1328,256,0,stream>>>(x_op_bf, Wc_op_t + (size_t)l*CQ*512, bias_op + l*CQ, qkv_op, CQ, 1, 20, 1280,
                                   x_m_bf, Wc_m_t + (size_t)l*CM*512, bias_m + l*CM, qkv_m, CM, 1, 12, 512);
    qk12_k<<<dim3(8,64,2),256,0,stream>>>(qkv_op, qkv_m, p_rel + l*24, Cn, W1, wpre, linv, S2f);
    msoftm_k<<<NMS,512,0,stream>>>(S2f, Ct, W2);
    agg12_k<<<576,256,0,stream>>>(W1, qkv_op, qkv_m, wpre, linv, agg_op, W2, agg_m);
    gemm2_k<<<272,256,0,stream>>>(agg_op, Wout_t + (size_t)(l*2+0)*262144, nullptr, o_op, 512, 0, 4, 256,
                                  agg_m, Wout_t + (size_t)(l*2+1)*262144, nullptr, o_m, 512, 0, 4, 512);
    gate2_k<<<1152,256,0,stream>>>(o_op, x_op, b_out + (size_t)(l*2+0)*512, skip + l*2+0,
                                   o_m, x_m, b_out + (size_t)(l*2+1)*512, skip + l*2+1, pstat, pstat_m);
    ln2_k<<<1152,256,0,stream>>>(o_op, last ? out : x_op, x_op_bf, ln_w + l*512, ln_b + l*512,
                                 o_m, last ? (out + TOPC) : x_m, x_m_bf, ln_w + l*512, ln_b + l*512,
                                 pstat, pstat_m);
  }

  // means (2 dispatches); final features already written to `out` by last ln2
  meanj_part_k<<<dim3(8,8),512,0,stream>>>(out, scratchJ);
  mean2_k<<<16,512,0,stream>>>(scratchJ, out);
}